// Round 12
// baseline (580.812 us; speedup 1.0000x reference)
//
#include <hip/hip_runtime.h>
#include <cfloat>
#include <cmath>
#include <stdint.h>

#define N 8192
#define D 512
#define K 16
#define RB 64      // rows per k_knn block (2 blocks/CU)
#define JS 2048    // cols per slice (4 slices)
#define NSL (N / JS)
#define JT 128     // j-tile width (JT=256 spills pfB[4]: R10)
#define NT (JS / JT)
#define KC 64      // k chunk (KC=128 spills: R4)
#define NCH (D / KC)
#define CAP 32     // survivor slots per row per pass
#define PB 64      // partial-reduce blocks for final

typedef __bf16 bf16x8 __attribute__((ext_vector_type(8)));
typedef __bf16 bf16x4 __attribute__((ext_vector_type(4)));
typedef float  f32x16 __attribute__((ext_vector_type(16)));
typedef float  f32x4  __attribute__((ext_vector_type(4)));

// ---------------- kernel 1: cast to bf16 + row norms + kadjG init ------------
__global__ __launch_bounds__(256)
void k_cast_sqnorm(const float* __restrict__ emb, float* __restrict__ sq,
                   __bf16* __restrict__ embh, int* __restrict__ kadjG) {
    int row = blockIdx.x * 4 + (threadIdx.x >> 6);
    int lane = threadIdx.x & 63;
    const float4* e = (const float4*)(emb + (size_t)row * D);
    float s = 0.f;
    #pragma unroll
    for (int c = 0; c < 2; c++) {
        float4 v = e[lane + 64 * c];
        s += v.x * v.x + v.y * v.y + v.z * v.z + v.w * v.w;
        bf16x4 h = { (__bf16)v.x, (__bf16)v.y, (__bf16)v.z, (__bf16)v.w };
        *(bf16x4*)&embh[(size_t)row * D + (size_t)(lane + 64 * c) * 4] = h;
    }
    for (int off = 32; off; off >>= 1) s += __shfl_down(s, off, 64);
    if (lane == 0) sq[row] = s;
    if (lane == 1) kadjG[row] = 0x7f7fffff;   // FLT_MAX bits
}

// ---------------- kernel 2: MFMA distance GEMM + streaming top-16 ------------
// R11 core (264 us: reg-prefetch, dbuf, 1 barrier/chunk, 2 blocks/CU, setprio,
// append fast-path, kadjG, ping-pong retry) + PAIRED SELECTION: the K-loop
// runs twice (two adjacent j-tiles into acc[0]/acc[1], 32 VGPRs), then ONE
// selection phase covers 256 columns. Selection phases per slice: 16 -> 8
// (half the threshold refreshes, retry barriers, merge invocations).
__global__ __launch_bounds__(512)
void k_knn(const __bf16* __restrict__ embh, const float* __restrict__ sq,
           float* __restrict__ pd2, int* __restrict__ pidx,
           int* __restrict__ kadjG) {
    __shared__ __align__(16) __bf16 As[2][RB][KC + 8];
    __shared__ __align__(16) __bf16 Bs[2][JT][KC + 8];
    __shared__ float svD[RB][CAP + 1];
    __shared__ int   svI[RB][CAP + 1];
    __shared__ float sqr[RB];
    __shared__ float kadj[RB];    // min(kmx_local, kG) - sq[row]
    __shared__ int   scount[RB];
    __shared__ int   again2[2];

    const int t   = threadIdx.x;
    const int rg  = blockIdx.x >> 2;
    const int sl  = blockIdx.x & 3;
    const int ib  = rg * RB;
    const int jsb = sl * JS;
    const int lane = t & 63, quad = lane >> 5, l31 = lane & 31;
    const int w  = t >> 6;            // 0..7
    const int wr = (w & 1) * 32;      // 2 row groups of 32
    const int wc = (w >> 1) * 32;     // 4 col groups of 32

    // persistent per-thread eighth of one row's top-16 (registers)
    const int mrow = t >> 3, tid8 = t & 7;
    float l0 = FLT_MAX, l1 = FLT_MAX;
    int   i0 = 0, i1 = 0;
    float kmx = FLT_MAX;              // uniform across each 8-lane group
    int   nfill = 0;                  // filled slots (uniform across group)

    if (t < RB) {
        sqr[t] = sq[ib + t];
        kadj[t] = FLT_MAX; scount[t] = 0;
    }
    __syncthreads();

    for (int jp = 0; jp < NT; jp += 2) {
        f32x16 acc[2];

        // ---- two K-loops (adjacent j-tiles), proven R9/R11 structure ----
        #pragma unroll
        for (int half = 0; half < 2; half++) {
            const int jb = jsb + (jp + half) * JT;
            acc[half] = (f32x16){};

            // stage chunk 0 into buffer 0
            {
                int row = t >> 3, g = t & 7;
                *(uint4*)&As[0][row][g * 8] = *(const uint4*)&embh[(size_t)(ib + row) * D + g * 8];
                #pragma unroll
                for (int q = 0; q < 2; q++) {
                    int s = t + 512 * q;
                    int brow = s >> 3, bg = s & 7;
                    *(uint4*)&Bs[0][brow][bg * 8] = *(const uint4*)&embh[(size_t)(jb + brow) * D + bg * 8];
                }
            }
            __syncthreads();

            uint4 pfA, pfB[2];
            for (int kc = 0; kc < NCH; kc++) {
                const int cur = kc & 1;
                if (kc + 1 < NCH) {            // register prefetch of next chunk
                    int k0 = (kc + 1) * KC;
                    {
                        int row = t >> 3, g = t & 7;
                        pfA = *(const uint4*)&embh[(size_t)(ib + row) * D + k0 + g * 8];
                    }
                    #pragma unroll
                    for (int q = 0; q < 2; q++) {
                        int s = t + 512 * q; int brow = s >> 3, bg = s & 7;
                        pfB[q] = *(const uint4*)&embh[(size_t)(jb + brow) * D + k0 + bg * 8];
                    }
                }
                __builtin_amdgcn_s_setprio(1);
                #pragma unroll
                for (int kk = 0; kk < KC / 16; kk++) {
                    int ko = kk * 16 + quad * 8;
                    bf16x8 a0 = *(const bf16x8*)&As[cur][wr + l31][ko];
                    bf16x8 b0 = *(const bf16x8*)&Bs[cur][wc + l31][ko];
                    acc[half] = __builtin_amdgcn_mfma_f32_32x32x16_bf16(a0, b0, acc[half], 0, 0, 0);
                }
                __builtin_amdgcn_s_setprio(0);
                if (kc + 1 < NCH) {            // write next chunk into other buffer
                    {
                        int row = t >> 3, g = t & 7;
                        *(uint4*)&As[cur ^ 1][row][g * 8] = pfA;
                    }
                    #pragma unroll
                    for (int q = 0; q < 2; q++) {
                        int s = t + 512 * q; int brow = s >> 3, bg = s & 7;
                        *(uint4*)&Bs[cur ^ 1][brow][bg * 8] = pfB[q];
                    }
                }
                __syncthreads();               // one barrier per chunk
            }
        }

        // ---- refresh threshold from the cross-slice global (once per pair) --
        if (t < RB) {
            float g = __int_as_float(kadjG[ib + t]);
            kadj[t] = fminf(kadj[t], g - sqr[t]);
        }
        if (t == 0) again2[0] = 0;
        __syncthreads();

        // ---- selection over BOTH tiles: survivor buffer + dedupe + retry ----
        const int jb0 = jsb + jp * JT, jb1 = jb0 + JT;
        float sqc0 = sq[jb0 + wc + l31];
        float sqc1 = sq[jb1 + wc + l31];
        uint32_t mask = 0;
        int pass = 0;
        while (true) {
            #pragma unroll
            for (int h = 0; h < 2; h++)
            #pragma unroll
            for (int reg = 0; reg < 16; reg++) {
                int bit = (h << 4) | reg;
                if ((mask >> bit) & 1) continue;
                int row_l = wr + ((reg & 3) + ((reg >> 2) << 3) + (quad << 2));
                float t2 = (h ? sqc1 : sqc0) - 2.f * acc[h][reg];
                if (t2 < kadj[row_l]) {
                    int j = (h ? jb1 : jb0) + wc + l31;
                    if (j != ib + row_l) {
                        int p = atomicAdd(&scount[row_l], 1);
                        if (p < CAP) {
                            svD[row_l][p] = t2 + sqr[row_l];
                            svI[row_l][p] = j;
                            mask |= (1u << bit);
                        }
                    }
                }
            }
            __syncthreads();               // B1: survivor buffer visible
            {
                int cnt = scount[mrow];
                if (cnt) {
                    int m = cnt < CAP ? cnt : CAP;
                    for (int p = 0; p < m; p++) {
                        float d2 = svD[mrow][p];
                        if (d2 < kmx) {
                            if (nfill < K) {
                                // append: zero-shuffle fill of empty slots
                                if ((nfill >> 1) == tid8) {
                                    int jv = svI[mrow][p];
                                    if ((nfill & 1) == 0) { l0 = d2; i0 = jv; }
                                    else                  { l1 = d2; i1 = jv; }
                                }
                                nfill++;
                                if (nfill == K) {   // establish kmx once full
                                    float lm = fmaxf(l0, l1);
                                    #pragma unroll
                                    for (int off = 1; off < 8; off <<= 1)
                                        lm = fmaxf(lm, __shfl_xor(lm, off, 64));
                                    kmx = lm;
                                }
                            } else {
                                // argmax-insert (R4-verified logic)
                                float mx = l0; int am = 0;
                                if (l1 > mx) { mx = l1; am = 1; }
                                int gam = (tid8 << 1) | am;
                                #pragma unroll
                                for (int off = 1; off < 8; off <<= 1) {
                                    float omx = __shfl_xor(mx, off, 64);
                                    int   oga = __shfl_xor(gam, off, 64);
                                    if (omx > mx || (omx == mx && oga < gam)) { mx = omx; gam = oga; }
                                }
                                if ((gam >> 1) == tid8) {
                                    int jv = svI[mrow][p];
                                    if ((gam & 1) == 0) { l0 = d2; i0 = jv; }
                                    else                { l1 = d2; i1 = jv; }
                                }
                                float lm = fmaxf(l0, l1);
                                #pragma unroll
                                for (int off = 1; off < 8; off <<= 1)
                                    lm = fmaxf(lm, __shfl_xor(lm, off, 64));
                                kmx = lm;
                            }
                        }
                    }
                    if (tid8 == 0) {
                        kadj[mrow] = fminf(kadj[mrow], kmx - sqr[mrow]);
                        scount[mrow] = 0;
                        if (cnt > CAP) again2[pass & 1] = 1;
                    }
                }
            }
            if (t == 0) again2[(pass + 1) & 1] = 0;
            __syncthreads();               // B2: flags final
            if (!again2[pass & 1]) break;
            pass++;
        }

        // publish tightened threshold for other slices of this row-group
        if (tid8 == 0 && kmx < FLT_MAX)
            atomicMin(&kadjG[ib + mrow], __float_as_int(kmx));
    }

    // write this thread's 2 register slots
    {
        size_t base = (size_t)(ib + mrow) * (NSL * K) + sl * K + tid8 * 2;
        pd2[base + 0] = l0; pd2[base + 1] = l1;
        pidx[base + 0] = i0; pidx[base + 1] = i1;
    }
}

// ---------------- kernel 3: fused merge + curvature --------------------------
// One wave per row i. Every lane runs the VERBATIM k_merge scan redundantly in
// registers (identical arithmetic => identical top-16 set/order), then picks
// its fragment row via a static cndmask chain (no runtime register indexing).
// Gram via MFMA 16x16x32 with the same fragment as A and B (R2-verified);
// gather stays global (embh is L2-resident; R11's big-LDS staging throttled
// occupancy for zero gain — reverted).
__global__ __launch_bounds__(256)
void k_curvm(const __bf16* __restrict__ embh, const float* __restrict__ pd2,
             const int* __restrict__ pidx, const float* __restrict__ ref_curv,
             float* __restrict__ curv_err, float* __restrict__ row_sum) {
    __shared__ float diagS[4][16];
    const int t = threadIdx.x;
    const int w = t >> 6, lane = t & 63;
    const int i = blockIdx.x * 4 + w;

    // ---- redundant per-lane merge of the 64 partial entries (== k_merge) ----
    float bd[K]; int bi[K];
    #pragma unroll
    for (int q = 0; q < K; q++) { bd[q] = FLT_MAX; bi[q] = 0; }
    float kmx = FLT_MAX;
    const float* pr = pd2 + (size_t)i * (NSL * K);
    const int*   pi = pidx + (size_t)i * (NSL * K);
    for (int s = 0; s < NSL * K; s++) {
        float d2 = pr[s];
        if (d2 < kmx) {
            int am = 0; float mx = bd[0];
            #pragma unroll
            for (int q = 1; q < K; q++) if (bd[q] > mx) { mx = bd[q]; am = q; }
            bd[am] = d2; bi[am] = pi[s];
            mx = bd[0];
            #pragma unroll
            for (int q = 1; q < K; q++) mx = fmaxf(mx, bd[q]);
            kmx = mx;
        }
    }
    float rs = 0.f;
    #pragma unroll
    for (int q = 0; q < K; q++) {
        float d2 = bd[q];
        rs += (d2 > 0.f) ? sqrtf(fmaxf(d2, 1e-12f)) : 0.f;
    }
    if (lane == 0) row_sum[i] = rs;

    // static select of this lane's neighbor row (cndmask chain, no scratch)
    int nidx = bi[0];
    #pragma unroll
    for (int q = 1; q < K; q++) if ((lane & 15) == q) nidx = bi[q];

    const __bf16* src = embh + (size_t)nidx * D + (lane >> 4) * 8;
    f32x4 acc = {};
    #pragma unroll
    for (int kc = 0; kc < D / 32; kc++) {
        bf16x8 a = *(const bf16x8*)(src + kc * 32);
        acc = __builtin_amdgcn_mfma_f32_16x16x32_bf16(a, a, acc, 0, 0, 0);
    }

    #pragma unroll
    for (int q = 0; q < 4; q++) {
        int r = (lane >> 4) * 4 + q;
        if (r == (lane & 15)) diagS[w][r] = acc[q];
    }
    __syncthreads();

    float s = 0.f;
    #pragma unroll
    for (int q = 0; q < 4; q++) {
        int r = (lane >> 4) * 4 + q, c = lane & 15;
        if (r != c) {
            float d2 = diagS[w][r] + diagS[w][c] - 2.f * acc[q];
            s += (d2 > 0.f) ? sqrtf(fmaxf(d2, 1e-12f)) : 0.f;
        }
    }
    #pragma unroll
    for (int off = 32; off; off >>= 1) s += __shfl_down(s, off, 64);

    if (lane == 0) {
        float inter_mean = (0.5f * s) / 120.f;
        float avg = rs / 16.f;
        float curv = inter_mean / (avg + 1e-8f);
        float diff = curv - ref_curv[i];
        curv_err[i] = diff * diff;
    }
}

// ---------------- kernel 4a: partial reduce (64 blocks) ----------------------
__global__ __launch_bounds__(256)
void k_part(const float* __restrict__ curv_err, const float* __restrict__ row_sum,
            const float* __restrict__ ref_dist, float* __restrict__ part) {
    const int b = blockIdx.x, t = threadIdx.x;
    const int gid = b * 256 + t;
    const int stride = PB * 256;
    float s1 = 0.f, s2 = 0.f, s3 = 0.f;
    for (int i = gid; i < N; i += stride) { s1 += curv_err[i]; s2 += row_sum[i]; }
    for (int i = gid; i < N * K; i += stride) s3 += ref_dist[i];
    for (int off = 32; off; off >>= 1) {
        s1 += __shfl_down(s1, off, 64);
        s2 += __shfl_down(s2, off, 64);
        s3 += __shfl_down(s3, off, 64);
    }
    __shared__ float a1[4], a2[4], a3[4];
    int w = t >> 6, lane = t & 63;
    if (lane == 0) { a1[w] = s1; a2[w] = s2; a3[w] = s3; }
    __syncthreads();
    if (t == 0) {
        float t1 = 0.f, t2 = 0.f, t3 = 0.f;
        #pragma unroll
        for (int q = 0; q < 4; q++) { t1 += a1[q]; t2 += a2[q]; t3 += a3[q]; }
        part[b] = t1; part[PB + b] = t2; part[2 * PB + b] = t3;
    }
}

// ---------------- kernel 4b: final scalar ------------------------------------
__global__ __launch_bounds__(64)
void k_final2(const float* __restrict__ part, float* __restrict__ out) {
    const int t = threadIdx.x;
    float s1 = part[t], s2 = part[PB + t], s3 = part[2 * PB + t];
    for (int off = 32; off; off >>= 1) {
        s1 += __shfl_down(s1, off, 64);
        s2 += __shfl_down(s2, off, 64);
        s3 += __shfl_down(s3, off, 64);
    }
    if (t == 0) {
        float curv_loss = s1 / (float)N;
        float dm = s2 / (float)(N * K);
        float rm = s3 / (float)(N * K);
        float d = dm - rm;
        out[0] = curv_loss + 0.1f * d * d;
    }
}

extern "C" void kernel_launch(void* const* d_in, const int* in_sizes, int n_in,
                              void* d_out, int out_size, void* d_ws, size_t ws_size,
                              hipStream_t stream) {
    const float* emb      = (const float*)d_in[0];
    const float* ref_curv = (const float*)d_in[1];
    const float* ref_dist = (const float*)d_in[2];
    float* out = (float*)d_out;

    float*  sq       = (float*)d_ws;                         // N
    float*  row_sum  = sq + N;                               // N
    float*  curv_err = row_sum + N;                          // N
    float*  pd2      = curv_err + N;                         // N*64
    int*    pidx     = (int*)(pd2 + (size_t)N * NSL * K);    // N*64
    __bf16* embh     = (__bf16*)(pidx + (size_t)N * NSL * K);// N*D bf16 (8 MB)
    float*  part     = (float*)(embh + (size_t)N * D);       // 3*PB
    int*    kadjG    = (int*)(part + 3 * PB);                // N

    k_cast_sqnorm<<<N / 4, 256, 0, stream>>>(emb, sq, embh, kadjG);
    k_knn<<<(N / RB) * NSL, 512, 0, stream>>>(embh, sq, pd2, pidx, kadjG);
    k_curvm<<<N / 4, 256, 0, stream>>>(embh, pd2, pidx, ref_curv, curv_err, row_sum);
    k_part<<<PB, 256, 0, stream>>>(curv_err, row_sum, ref_dist, part);
    k_final2<<<1, 64, 0, stream>>>(part, out);
}

// Round 13
// 361.898 us; speedup vs baseline: 1.6049x; 1.6049x over previous
//
#include <hip/hip_runtime.h>
#include <cfloat>
#include <cmath>
#include <stdint.h>

#define N 8192
#define D 512
#define K 16
#define RB 64      // rows per k_knn block (2 blocks/CU)
#define JS 2048    // cols per slice (4 slices)
#define NSL (N / JS)
#define JT 128     // j-tile width (JT=256 spills pfB[4]: R10. Keep 128.)
#define NT (JS / JT)
#define KC 64      // k chunk (KC=128 spills: R4)
#define NCH (D / KC)
#define CAP 32     // survivor slots per row per pass
#define PB 64      // partial-reduce blocks for final

typedef __bf16 bf16x8 __attribute__((ext_vector_type(8)));
typedef __bf16 bf16x4 __attribute__((ext_vector_type(4)));
typedef float  f32x16 __attribute__((ext_vector_type(16)));
typedef float  f32x4  __attribute__((ext_vector_type(4)));

// ---------------- kernel 1: cast to bf16 + row norms + kadjG init ------------
__global__ __launch_bounds__(256)
void k_cast_sqnorm(const float* __restrict__ emb, float* __restrict__ sq,
                   __bf16* __restrict__ embh, int* __restrict__ kadjG) {
    int row = blockIdx.x * 4 + (threadIdx.x >> 6);
    int lane = threadIdx.x & 63;
    const float4* e = (const float4*)(emb + (size_t)row * D);
    float s = 0.f;
    #pragma unroll
    for (int c = 0; c < 2; c++) {
        float4 v = e[lane + 64 * c];
        s += v.x * v.x + v.y * v.y + v.z * v.z + v.w * v.w;
        bf16x4 h = { (__bf16)v.x, (__bf16)v.y, (__bf16)v.z, (__bf16)v.w };
        *(bf16x4*)&embh[(size_t)row * D + (size_t)(lane + 64 * c) * 4] = h;
    }
    for (int off = 32; off; off >>= 1) s += __shfl_down(s, off, 64);
    if (lane == 0) sq[row] = s;
    if (lane == 1) kadjG[row] = 0x7f7fffff;   // FLT_MAX bits
}

// ---------------- kernel 2: MFMA distance GEMM + streaming top-16 ------------
// EXACT R11 core (measured 264 us): reg-prefetch <=3 uint4, dbuf, 1 barrier/
// chunk, 2 blocks/CU, setprio around MFMA, append fast-path, kadjG cross-slice
// threshold, ping-pong retry. R12's paired-selection variant (unroll-doubled
// K-loop body, acc[2] live across both loops) collapsed occupancy 44->24% and
// doubled duration — single-tile K-loop restored verbatim.
__global__ __launch_bounds__(512)
void k_knn(const __bf16* __restrict__ embh, const float* __restrict__ sq,
           float* __restrict__ pd2, int* __restrict__ pidx,
           int* __restrict__ kadjG) {
    __shared__ __align__(16) __bf16 As[2][RB][KC + 8];
    __shared__ __align__(16) __bf16 Bs[2][JT][KC + 8];
    __shared__ float svD[RB][CAP + 1];
    __shared__ int   svI[RB][CAP + 1];
    __shared__ float sqr[RB];
    __shared__ float kadj[RB];    // min(kmx_local, kG) - sq[row]
    __shared__ int   scount[RB];
    __shared__ int   again2[2];

    const int t   = threadIdx.x;
    const int rg  = blockIdx.x >> 2;
    const int sl  = blockIdx.x & 3;
    const int ib  = rg * RB;
    const int jsb = sl * JS;
    const int lane = t & 63, quad = lane >> 5, l31 = lane & 31;
    const int w  = t >> 6;            // 0..7
    const int wr = (w & 1) * 32;      // 2 row groups of 32
    const int wc = (w >> 1) * 32;     // 4 col groups of 32

    // persistent per-thread eighth of one row's top-16 (registers)
    const int mrow = t >> 3, tid8 = t & 7;
    float l0 = FLT_MAX, l1 = FLT_MAX;
    int   i0 = 0, i1 = 0;
    float kmx = FLT_MAX;              // uniform across each 8-lane group
    int   nfill = 0;                  // filled slots (uniform across group)

    if (t < RB) {
        sqr[t] = sq[ib + t];
        kadj[t] = FLT_MAX; scount[t] = 0;
    }
    __syncthreads();

    for (int jt = 0; jt < NT; jt++) {
        const int jb = jsb + jt * JT;
        f32x16 acc = {};

        // stage chunk 0 into buffer 0: A 512 slots (1/thread), B 1024 (2/thread)
        {
            int row = t >> 3, g = t & 7;
            *(uint4*)&As[0][row][g * 8] = *(const uint4*)&embh[(size_t)(ib + row) * D + g * 8];
            #pragma unroll
            for (int q = 0; q < 2; q++) {
                int s = t + 512 * q;
                int brow = s >> 3, bg = s & 7;
                *(uint4*)&Bs[0][brow][bg * 8] = *(const uint4*)&embh[(size_t)(jb + brow) * D + bg * 8];
            }
        }
        __syncthreads();

        uint4 pfA, pfB[2];
        for (int kc = 0; kc < NCH; kc++) {
            const int cur = kc & 1;
            if (kc + 1 < NCH) {            // register prefetch of next chunk
                int k0 = (kc + 1) * KC;
                {
                    int row = t >> 3, g = t & 7;
                    pfA = *(const uint4*)&embh[(size_t)(ib + row) * D + k0 + g * 8];
                }
                #pragma unroll
                for (int q = 0; q < 2; q++) {
                    int s = t + 512 * q; int brow = s >> 3, bg = s & 7;
                    pfB[q] = *(const uint4*)&embh[(size_t)(jb + brow) * D + k0 + bg * 8];
                }
            }
            __builtin_amdgcn_s_setprio(1);
            #pragma unroll
            for (int kk = 0; kk < KC / 16; kk++) {
                int ko = kk * 16 + quad * 8;
                bf16x8 a0 = *(const bf16x8*)&As[cur][wr + l31][ko];
                bf16x8 b0 = *(const bf16x8*)&Bs[cur][wc + l31][ko];
                acc = __builtin_amdgcn_mfma_f32_32x32x16_bf16(a0, b0, acc, 0, 0, 0);
            }
            __builtin_amdgcn_s_setprio(0);
            if (kc + 1 < NCH) {            // write next chunk into other buffer
                {
                    int row = t >> 3, g = t & 7;
                    *(uint4*)&As[cur ^ 1][row][g * 8] = pfA;
                }
                #pragma unroll
                for (int q = 0; q < 2; q++) {
                    int s = t + 512 * q; int brow = s >> 3, bg = s & 7;
                    *(uint4*)&Bs[cur ^ 1][brow][bg * 8] = pfB[q];
                }
            }
            __syncthreads();               // one barrier per chunk
        }

        // ---- refresh threshold from the cross-slice global ----
        if (t < RB) {
            float g = __int_as_float(kadjG[ib + t]);
            kadj[t] = fminf(kadj[t], g - sqr[t]);
        }
        if (t == 0) again2[0] = 0;
        __syncthreads();

        // ---- selection: capped survivor buffer + dedupe mask + retry ----
        float sqc0 = sq[jb + wc + l31];
        uint32_t mask = 0;
        int pass = 0;
        while (true) {
            #pragma unroll
            for (int reg = 0; reg < 16; reg++) {
                if ((mask >> reg) & 1) continue;
                int row_l = wr + ((reg & 3) + ((reg >> 2) << 3) + (quad << 2));
                float t2 = sqc0 - 2.f * acc[reg];
                if (t2 < kadj[row_l]) {
                    int j = jb + wc + l31;
                    if (j != ib + row_l) {
                        int p = atomicAdd(&scount[row_l], 1);
                        if (p < CAP) {
                            svD[row_l][p] = t2 + sqr[row_l];
                            svI[row_l][p] = j;
                            mask |= (1u << reg);
                        }
                    }
                }
            }
            __syncthreads();               // B1: survivor buffer visible
            {
                int cnt = scount[mrow];
                if (cnt) {
                    int m = cnt < CAP ? cnt : CAP;
                    for (int p = 0; p < m; p++) {
                        float d2 = svD[mrow][p];
                        if (d2 < kmx) {
                            if (nfill < K) {
                                // append: zero-shuffle fill of empty slots
                                if ((nfill >> 1) == tid8) {
                                    int jv = svI[mrow][p];
                                    if ((nfill & 1) == 0) { l0 = d2; i0 = jv; }
                                    else                  { l1 = d2; i1 = jv; }
                                }
                                nfill++;
                                if (nfill == K) {   // establish kmx once full
                                    float lm = fmaxf(l0, l1);
                                    #pragma unroll
                                    for (int off = 1; off < 8; off <<= 1)
                                        lm = fmaxf(lm, __shfl_xor(lm, off, 64));
                                    kmx = lm;
                                }
                            } else {
                                // argmax-insert (R4-verified logic)
                                float mx = l0; int am = 0;
                                if (l1 > mx) { mx = l1; am = 1; }
                                int gam = (tid8 << 1) | am;
                                #pragma unroll
                                for (int off = 1; off < 8; off <<= 1) {
                                    float omx = __shfl_xor(mx, off, 64);
                                    int   oga = __shfl_xor(gam, off, 64);
                                    if (omx > mx || (omx == mx && oga < gam)) { mx = omx; gam = oga; }
                                }
                                if ((gam >> 1) == tid8) {
                                    int jv = svI[mrow][p];
                                    if ((gam & 1) == 0) { l0 = d2; i0 = jv; }
                                    else                { l1 = d2; i1 = jv; }
                                }
                                float lm = fmaxf(l0, l1);
                                #pragma unroll
                                for (int off = 1; off < 8; off <<= 1)
                                    lm = fmaxf(lm, __shfl_xor(lm, off, 64));
                                kmx = lm;
                            }
                        }
                    }
                    if (tid8 == 0) {
                        kadj[mrow] = fminf(kadj[mrow], kmx - sqr[mrow]);
                        scount[mrow] = 0;
                        if (cnt > CAP) again2[pass & 1] = 1;
                    }
                }
            }
            if (t == 0) again2[(pass + 1) & 1] = 0;
            __syncthreads();               // B2: flags final
            if (!again2[pass & 1]) break;
            pass++;
        }

        // publish tightened threshold for other slices of this row-group
        if (tid8 == 0 && kmx < FLT_MAX)
            atomicMin(&kadjG[ib + mrow], __float_as_int(kmx));
    }

    // write this thread's 2 register slots
    {
        size_t base = (size_t)(ib + mrow) * (NSL * K) + sl * K + tid8 * 2;
        pd2[base + 0] = l0; pd2[base + 1] = l1;
        pidx[base + 0] = i0; pidx[base + 1] = i1;
    }
}

// ---------------- kernel 3: merge 4 partial lists per row --------------------
__global__ __launch_bounds__(256)
void k_merge(const float* __restrict__ pd2, const int* __restrict__ pidx,
             int* __restrict__ knn, float* __restrict__ row_sum) {
    int row = blockIdx.x * 256 + threadIdx.x;
    float bd[K]; int bi[K];
    #pragma unroll
    for (int q = 0; q < K; q++) { bd[q] = FLT_MAX; bi[q] = 0; }
    float kmx = FLT_MAX;
    const float* pr = pd2 + (size_t)row * (NSL * K);
    const int*   pi = pidx + (size_t)row * (NSL * K);
    for (int s = 0; s < NSL * K; s++) {
        float d2 = pr[s];
        if (d2 < kmx) {
            int am = 0; float mx = bd[0];
            #pragma unroll
            for (int q = 1; q < K; q++) if (bd[q] > mx) { mx = bd[q]; am = q; }
            bd[am] = d2; bi[am] = pi[s];
            mx = bd[0];
            #pragma unroll
            for (int q = 1; q < K; q++) mx = fmaxf(mx, bd[q]);
            kmx = mx;
        }
    }
    float s = 0.f;
    #pragma unroll
    for (int q = 0; q < K; q++) {
        float d2 = bd[q];
        s += (d2 > 0.f) ? sqrtf(fmaxf(d2, 1e-12f)) : 0.f;
        knn[(size_t)row * K + q] = bi[q];
    }
    row_sum[row] = s;
}

// ---------------- kernel 4: per-row curvature via MFMA gram ------------------
// One wave per row i. Coalesced LDS staging of the 16 neighbor rows, then
// MFMA 16x16x32 with the same fragment as A and B (R2-verified layout).
// Exact R11 form (measured as part of the 363.9 us total).
__global__ __launch_bounds__(256)
void k_curv(const __bf16* __restrict__ embh, const int* __restrict__ knn_idx,
            const float* __restrict__ row_sum, const float* __restrict__ ref_curv,
            float* __restrict__ curv_err) {
    __shared__ __align__(16) __bf16 nb[4][K][D + 8];
    __shared__ float diagS[4][16];
    const int t = threadIdx.x;
    const int w = t >> 6, lane = t & 63;
    const int i = blockIdx.x * 4 + w;

    // coalesced stage of the 16 neighbor rows for this wave
    #pragma unroll
    for (int r = 0; r < K; r++) {
        int nidx = knn_idx[(size_t)i * K + r];
        *(uint4*)&nb[w][r][lane * 8] =
            *(const uint4*)&embh[(size_t)nidx * D + lane * 8];
    }
    __syncthreads();

    f32x4 acc = {};
    #pragma unroll
    for (int kc = 0; kc < D / 32; kc++) {
        bf16x8 a = *(const bf16x8*)&nb[w][lane & 15][(lane >> 4) * 8 + kc * 32];
        acc = __builtin_amdgcn_mfma_f32_16x16x32_bf16(a, a, acc, 0, 0, 0);
    }

    // write diagonal entries gram[c][c]
    #pragma unroll
    for (int q = 0; q < 4; q++) {
        int r = (lane >> 4) * 4 + q;
        if (r == (lane & 15)) diagS[w][r] = acc[q];
    }
    __syncthreads();

    float s = 0.f;
    #pragma unroll
    for (int q = 0; q < 4; q++) {
        int r = (lane >> 4) * 4 + q, c = lane & 15;
        if (r != c) {
            float d2 = diagS[w][r] + diagS[w][c] - 2.f * acc[q];
            s += (d2 > 0.f) ? sqrtf(fmaxf(d2, 1e-12f)) : 0.f;
        }
    }
    #pragma unroll
    for (int off = 32; off; off >>= 1) s += __shfl_down(s, off, 64);

    if (lane == 0) {
        float inter_mean = (0.5f * s) / 120.f;
        float avg = row_sum[i] / 16.f;
        float curv = inter_mean / (avg + 1e-8f);
        float diff = curv - ref_curv[i];
        curv_err[i] = diff * diff;
    }
}

// ---------------- kernel 5a: partial reduce (64 blocks) ----------------------
__global__ __launch_bounds__(256)
void k_part(const float* __restrict__ curv_err, const float* __restrict__ row_sum,
            const float* __restrict__ ref_dist, float* __restrict__ part) {
    const int b = blockIdx.x, t = threadIdx.x;
    const int gid = b * 256 + t;
    const int stride = PB * 256;
    float s1 = 0.f, s2 = 0.f, s3 = 0.f;
    for (int i = gid; i < N; i += stride) { s1 += curv_err[i]; s2 += row_sum[i]; }
    for (int i = gid; i < N * K; i += stride) s3 += ref_dist[i];
    for (int off = 32; off; off >>= 1) {
        s1 += __shfl_down(s1, off, 64);
        s2 += __shfl_down(s2, off, 64);
        s3 += __shfl_down(s3, off, 64);
    }
    __shared__ float a1[4], a2[4], a3[4];
    int w = t >> 6, lane = t & 63;
    if (lane == 0) { a1[w] = s1; a2[w] = s2; a3[w] = s3; }
    __syncthreads();
    if (t == 0) {
        float t1 = 0.f, t2 = 0.f, t3 = 0.f;
        #pragma unroll
        for (int q = 0; q < 4; q++) { t1 += a1[q]; t2 += a2[q]; t3 += a3[q]; }
        part[b] = t1; part[PB + b] = t2; part[2 * PB + b] = t3;
    }
}

// ---------------- kernel 5b: final scalar ------------------------------------
__global__ __launch_bounds__(64)
void k_final2(const float* __restrict__ part, float* __restrict__ out) {
    const int t = threadIdx.x;
    float s1 = part[t], s2 = part[PB + t], s3 = part[2 * PB + t];
    for (int off = 32; off; off >>= 1) {
        s1 += __shfl_down(s1, off, 64);
        s2 += __shfl_down(s2, off, 64);
        s3 += __shfl_down(s3, off, 64);
    }
    if (t == 0) {
        float curv_loss = s1 / (float)N;
        float dm = s2 / (float)(N * K);
        float rm = s3 / (float)(N * K);
        float d = dm - rm;
        out[0] = curv_loss + 0.1f * d * d;
    }
}

extern "C" void kernel_launch(void* const* d_in, const int* in_sizes, int n_in,
                              void* d_out, int out_size, void* d_ws, size_t ws_size,
                              hipStream_t stream) {
    const float* emb      = (const float*)d_in[0];
    const float* ref_curv = (const float*)d_in[1];
    const float* ref_dist = (const float*)d_in[2];
    float* out = (float*)d_out;

    float*  sq       = (float*)d_ws;                         // N
    float*  row_sum  = sq + N;                               // N
    float*  curv_err = row_sum + N;                          // N
    float*  pd2      = curv_err + N;                         // N*64
    int*    pidx     = (int*)(pd2 + (size_t)N * NSL * K);    // N*64
    int*    knn      = pidx + (size_t)N * NSL * K;           // N*K
    __bf16* embh     = (__bf16*)(knn + (size_t)N * K);       // N*D bf16 (8 MB)
    float*  part     = (float*)(embh + (size_t)N * D);       // 3*PB
    int*    kadjG    = (int*)(part + 3 * PB);                // N

    k_cast_sqnorm<<<N / 4, 256, 0, stream>>>(emb, sq, embh, kadjG);
    k_knn<<<(N / RB) * NSL, 512, 0, stream>>>(embh, sq, pd2, pidx, kadjG);
    k_merge<<<N / 256, 256, 0, stream>>>(pd2, pidx, knn, row_sum);
    k_curv<<<N / 4, 256, 0, stream>>>(embh, knn, row_sum, ref_curv, curv_err);
    k_part<<<PB, 256, 0, stream>>>(curv_err, row_sum, ref_dist, part);
    k_final2<<<1, 64, 0, stream>>>(part, out);
}